// Round 6
// baseline (279.060 us; speedup 1.0000x reference)
//
#include <hip/hip_runtime.h>
#include <hip/hip_bf16.h>

#define HDIM 128
#define NB   1024          // sort bins: bin = src >> 7 (max 99999>>7 = 781 < 1024)

typedef short bf16x8 __attribute__((ext_vector_type(8)));
typedef float f32x4 __attribute__((ext_vector_type(4)));

__device__ __forceinline__ short f2bf(float f) {
    __hip_bfloat16 h = __float2bfloat16(f);
    return __builtin_bit_cast(short, h);
}

__device__ __forceinline__ float bf2f(short s) {
    unsigned u = ((unsigned)(unsigned short)s) << 16;
    return __builtin_bit_cast(float, u);
}

// B-fragment read from swizzled WT[n][k] LDS image
__device__ __forceinline__ bf16x8 ldB(const short* sW, int n, int chunk) {
    return *(const bf16x8*)(sW + n * HDIM + ((chunk ^ (n & 7)) << 3));
}

__device__ __forceinline__ bf16x8 gatherA_f32(const float* xs, const float* xd, int k0) {
    float4 a0 = *(const float4*)(xs + k0);
    float4 a1 = *(const float4*)(xs + k0 + 4);
    float4 c0 = *(const float4*)(xd + k0);
    float4 c1 = *(const float4*)(xd + k0 + 4);
    bf16x8 r = { f2bf(a0.x * c0.x), f2bf(a0.y * c0.y), f2bf(a0.z * c0.z), f2bf(a0.w * c0.w),
                 f2bf(a1.x * c1.x), f2bf(a1.y * c1.y), f2bf(a1.z * c1.z), f2bf(a1.w * c1.w) };
    return r;
}

__global__ void cvt_kernel(const float* __restrict__ x, unsigned short* __restrict__ xb, int n4) {
    int i = blockIdx.x * blockDim.x + threadIdx.x;
    const int stride = gridDim.x * blockDim.x;
    for (; i < n4; i += stride) {
        float4 v = ((const float4*)x)[i];
        ushort4 o;
        o.x = (unsigned short)f2bf(v.x);
        o.y = (unsigned short)f2bf(v.y);
        o.z = (unsigned short)f2bf(v.z);
        o.w = (unsigned short)f2bf(v.w);
        ((ushort4*)xb)[i] = o;
    }
}

// ---- counting sort by src>>7 ----
__global__ void hist_kernel(const int* __restrict__ src, int* __restrict__ hist, int E) {
    __shared__ int h[NB];
    for (int i = threadIdx.x; i < NB; i += blockDim.x) h[i] = 0;
    __syncthreads();
    int i = blockIdx.x * blockDim.x + threadIdx.x;
    for (; i < E; i += gridDim.x * blockDim.x) atomicAdd(&h[src[i] >> 7], 1);
    __syncthreads();
    for (int i2 = threadIdx.x; i2 < NB; i2 += blockDim.x)
        if (h[i2]) atomicAdd(&hist[i2], h[i2]);
}

__global__ void scan_kernel(const int* __restrict__ hist, int* __restrict__ cursor) {
    __shared__ int s[NB];
    const int t = threadIdx.x;
    int v = hist[t];
    s[t] = v;
    __syncthreads();
    for (int off = 1; off < NB; off <<= 1) {
        int add = (t >= off) ? s[t - off] : 0;
        __syncthreads();
        s[t] += add;
        __syncthreads();
    }
    cursor[t] = s[t] - v;   // exclusive offsets
}

__global__ void scatter_kernel(const int* __restrict__ src, const int* __restrict__ dst,
                               int* __restrict__ cursor,
                               int* __restrict__ ssrc, int* __restrict__ sdst,
                               int* __restrict__ perm, int E) {
    int i = blockIdx.x * blockDim.x + threadIdx.x;
    for (; i < E; i += gridDim.x * blockDim.x) {
        int sv = src[i];
        int p = atomicAdd(&cursor[sv >> 7], 1);
        ssrc[p] = sv;
        sdst[p] = dst[i];
        perm[p] = i;
    }
}

// MODE: 0 = fp32 direct (no ws), 1 = bf16 unsorted (R2 path), 2 = bf16 sorted + perm scatter
// 256 threads, 4 waves x 32 edges; LDS 80 KB -> 2 blocks/CU (8 waves/CU); ~256 total regs OK.
template<int MODE>
__global__ __launch_bounds__(256, 2)
void edge_mlp_kernel(const float* __restrict__ x,
                     const unsigned short* __restrict__ xb,
                     const int* __restrict__ ssrc,
                     const int* __restrict__ sdst,
                     const int* __restrict__ perm,
                     const float* __restrict__ W1, const float* __restrict__ b1,
                     const float* __restrict__ W2, const float* __restrict__ b2,
                     const float* __restrict__ W3, const float* __restrict__ b3,
                     float* __restrict__ out, int E, int ntiles)
{
    __shared__ short sW1[HDIM * HDIM];      // 32 KB
    __shared__ short sW2[HDIM * HDIM];      // 32 KB
    __shared__ short sH1[4][32 * 64];       // 16 KB

    const int tid = threadIdx.x;

    // stage weights fp32 [k][n] -> LDS bf16 WT[n][k], swizzled
    {
        const int n  = tid & 127;
        const int kh = tid >> 7;
        for (int c = 0; c < 8; ++c) {
            const int kc = kh * 8 + c;
            const int k0 = kc * 8;
            short v1[8], v2[8];
            #pragma unroll
            for (int j = 0; j < 8; ++j) {
                v1[j] = f2bf(W1[(k0 + j) * HDIM + n]);
                v2[j] = f2bf(W2[(k0 + j) * HDIM + n]);
            }
            const int off = n * HDIM + ((kc ^ (n & 7)) << 3);
            bf16x8 t1 = { v1[0], v1[1], v1[2], v1[3], v1[4], v1[5], v1[6], v1[7] };
            bf16x8 t2 = { v2[0], v2[1], v2[2], v2[3], v2[4], v2[5], v2[6], v2[7] };
            *(bf16x8*)(sW1 + off) = t1;
            *(bf16x8*)(sW2 + off) = t2;
        }
    }
    __syncthreads();

    const int w    = tid >> 6;
    const int lane = tid & 63;
    const int g    = lane >> 4;
    const int e16  = lane & 15;
    short* myH1 = &sH1[w][0];

    float b1v[8], b2v[8], w3v[8];
    #pragma unroll
    for (int nt = 0; nt < 8; ++nt) {
        b1v[nt] = b1[nt * 16 + e16];
        b2v[nt] = b2[nt * 16 + e16];
        w3v[nt] = W3[nt * 16 + e16];
    }
    const float b3s = b3[0];

    // tile range: MODE2 = contiguous chunk (sorted locality), else grid-stride
    int t0, t1e, tstep;
    if constexpr (MODE == 2) {
        const int tp = (ntiles + gridDim.x - 1) / gridDim.x;
        t0 = blockIdx.x * tp;
        t1e = t0 + tp < ntiles ? t0 + tp : ntiles;
        tstep = 1;
    } else {
        t0 = blockIdx.x;
        t1e = ntiles;
        tstep = gridDim.x;
    }
    if (t0 >= t1e) return;

    int tile = t0;
    int s0, d0, s1, d1;
    {
        const int base = (tile << 7) + (w << 5);
        int a0 = base + e16;       a0 = a0 < E ? a0 : 0;
        int a1 = base + 16 + e16;  a1 = a1 < E ? a1 : 0;
        s0 = ssrc[a0]; d0 = sdst[a0]; s1 = ssrc[a1]; d1 = sdst[a1];
    }
    bf16x8 rS0[4], rD0[4], rS1[4], rD1[4];
    if constexpr (MODE >= 1) {
        const unsigned short* pxs0 = xb + (size_t)s0 * HDIM;
        const unsigned short* pxd0 = xb + (size_t)d0 * HDIM;
        const unsigned short* pxs1 = xb + (size_t)s1 * HDIM;
        const unsigned short* pxd1 = xb + (size_t)d1 * HDIM;
        #pragma unroll
        for (int t = 0; t < 4; ++t) {
            const int k0 = t * 32 + g * 8;
            rS0[t] = *(const bf16x8*)(pxs0 + k0);
            rD0[t] = *(const bf16x8*)(pxd0 + k0);
            rS1[t] = *(const bf16x8*)(pxs1 + k0);
            rD1[t] = *(const bf16x8*)(pxd1 + k0);
        }
    }

    for (;;) {
        const int nxt = tile + tstep;
        const bool hasNext = nxt < t1e;

        int ns0, nd0, ns1, nd1;
        {
            const int nb = hasNext ? (nxt << 7) + (w << 5) : 0;
            int a0 = nb + e16;       a0 = a0 < E ? a0 : 0;
            int a1 = nb + 16 + e16;  a1 = a1 < E ? a1 : 0;
            ns0 = ssrc[a0]; nd0 = sdst[a0]; ns1 = ssrc[a1]; nd1 = sdst[a1];
        }

        const int base = (tile << 7) + (w << 5);

        // ---------- GEMM1 ----------
        f32x4 acc[2][8];
        #pragma unroll
        for (int nt = 0; nt < 8; ++nt) {
            f32x4 iv = { b1v[nt], b1v[nt], b1v[nt], b1v[nt] };
            acc[0][nt] = iv;
            acc[1][nt] = iv;
        }

        if constexpr (MODE >= 1) {
            #pragma unroll
            for (int t = 0; t < 4; ++t) {
                bf16x8 a0, a1;
                #pragma unroll
                for (int j = 0; j < 8; ++j) {
                    a0[j] = f2bf(bf2f(rS0[t][j]) * bf2f(rD0[t][j]));
                    a1[j] = f2bf(bf2f(rS1[t][j]) * bf2f(rD1[t][j]));
                }
                #pragma unroll
                for (int nt = 0; nt < 8; ++nt) {
                    bf16x8 bb = ldB(sW1, nt * 16 + e16, t * 4 + g);
                    acc[0][nt] = __builtin_amdgcn_mfma_f32_16x16x32_bf16(a0, bb, acc[0][nt], 0, 0, 0);
                    acc[1][nt] = __builtin_amdgcn_mfma_f32_16x16x32_bf16(a1, bb, acc[1][nt], 0, 0, 0);
                }
            }
        } else {
            const float* xs0 = x + (size_t)s0 * HDIM;
            const float* xd0 = x + (size_t)d0 * HDIM;
            const float* xs1 = x + (size_t)s1 * HDIM;
            const float* xd1 = x + (size_t)d1 * HDIM;
            #pragma unroll
            for (int t = 0; t < 4; ++t) {
                const int k0 = t * 32 + g * 8;
                bf16x8 a0 = gatherA_f32(xs0, xd0, k0);
                bf16x8 a1 = gatherA_f32(xs1, xd1, k0);
                #pragma unroll
                for (int nt = 0; nt < 8; ++nt) {
                    bf16x8 bb = ldB(sW1, nt * 16 + e16, t * 4 + g);
                    acc[0][nt] = __builtin_amdgcn_mfma_f32_16x16x32_bf16(a0, bb, acc[0][nt], 0, 0, 0);
                    acc[1][nt] = __builtin_amdgcn_mfma_f32_16x16x32_bf16(a1, bb, acc[1][nt], 0, 0, 0);
                }
            }
        }

        // issue next tile's raw gathers; latency hides under GEMM2
        bf16x8 nS0[4], nD0[4], nS1[4], nD1[4];
        if constexpr (MODE >= 1) {
            const unsigned short* pxs0 = xb + (size_t)ns0 * HDIM;
            const unsigned short* pxd0 = xb + (size_t)nd0 * HDIM;
            const unsigned short* pxs1 = xb + (size_t)ns1 * HDIM;
            const unsigned short* pxd1 = xb + (size_t)nd1 * HDIM;
            #pragma unroll
            for (int t = 0; t < 4; ++t) {
                const int k0 = t * 32 + g * 8;
                nS0[t] = *(const bf16x8*)(pxs0 + k0);
                nD0[t] = *(const bf16x8*)(pxd0 + k0);
                nS1[t] = *(const bf16x8*)(pxs1 + k0);
                nD1[t] = *(const bf16x8*)(pxd1 + k0);
            }
        }

        // ---------- GEMM2 ----------
        f32x4 acc2[2][8];
        #pragma unroll
        for (int nt = 0; nt < 8; ++nt) {
            f32x4 iv = { b2v[nt], b2v[nt], b2v[nt], b2v[nt] };
            acc2[0][nt] = iv;
            acc2[1][nt] = iv;
        }
        #pragma unroll
        for (int khf = 0; khf < 2; ++khf) {
            #pragma unroll
            for (int ntl = 0; ntl < 4; ++ntl) {
                const int nt = khf * 4 + ntl;
                #pragma unroll
                for (int mt = 0; mt < 2; ++mt) {
                    #pragma unroll
                    for (int r = 0; r < 4; ++r) {
                        const int e  = mt * 16 + g * 4 + r;
                        const int kk = ntl * 16 + e16;
                        float v = acc[mt][nt][r];
                        v = v > 0.0f ? v : 0.0f;
                        myH1[e * 64 + (((kk >> 3) ^ (e & 7)) << 3) + (kk & 7)] = f2bf(v);
                    }
                }
            }
            #pragma unroll
            for (int tl = 0; tl < 2; ++tl) {
                const int ck = tl * 4 + g;
                bf16x8 a0 = *(const bf16x8*)(myH1 + e16 * 64 + ((ck ^ (e16 & 7)) << 3));
                bf16x8 a1 = *(const bf16x8*)(myH1 + (e16 + 16) * 64 + ((ck ^ ((e16 + 16) & 7)) << 3));
                const int t2 = khf * 2 + tl;
                #pragma unroll
                for (int nt = 0; nt < 8; ++nt) {
                    bf16x8 bb = ldB(sW2, nt * 16 + e16, t2 * 4 + g);
                    acc2[0][nt] = __builtin_amdgcn_mfma_f32_16x16x32_bf16(a0, bb, acc2[0][nt], 0, 0, 0);
                    acc2[1][nt] = __builtin_amdgcn_mfma_f32_16x16x32_bf16(a1, bb, acc2[1][nt], 0, 0, 0);
                }
            }
        }

        // ---------- epilogue ----------
        #pragma unroll
        for (int mt = 0; mt < 2; ++mt) {
            float p0 = 0.f, p1 = 0.f, p2 = 0.f, p3 = 0.f;
            #pragma unroll
            for (int nt = 0; nt < 8; ++nt) {
                f32x4 v = acc2[mt][nt];
                float r0 = v[0] > 0.f ? v[0] : 0.f;
                float r1 = v[1] > 0.f ? v[1] : 0.f;
                float r2 = v[2] > 0.f ? v[2] : 0.f;
                float r3 = v[3] > 0.f ? v[3] : 0.f;
                p0 += r0 * w3v[nt];
                p1 += r1 * w3v[nt];
                p2 += r2 * w3v[nt];
                p3 += r3 * w3v[nt];
            }
            #pragma unroll
            for (int off = 1; off < 16; off <<= 1) {
                p0 += __shfl_xor(p0, off);
                p1 += __shfl_xor(p1, off);
                p2 += __shfl_xor(p2, off);
                p3 += __shfl_xor(p3, off);
            }
            if (e16 == 0) {
                const int eb = base + mt * 16 + g * 4;
                float pv[4] = { p0, p1, p2, p3 };
                #pragma unroll
                for (int j = 0; j < 4; ++j) {
                    if (eb + j < E) {
                        if constexpr (MODE == 2) out[perm[eb + j]] = pv[j] + b3s;
                        else                     out[eb + j]       = pv[j] + b3s;
                    }
                }
            }
        }

        if (!hasNext) break;
        tile = nxt;
        s0 = ns0; d0 = nd0; s1 = ns1; d1 = nd1;
        if constexpr (MODE >= 1) {
            #pragma unroll
            for (int t = 0; t < 4; ++t) {
                rS0[t] = nS0[t]; rD0[t] = nD0[t];
                rS1[t] = nS1[t]; rD1[t] = nD1[t];
            }
        }
    }
}

static inline size_t align256(size_t v) { return (v + 255) & ~(size_t)255; }

extern "C" void kernel_launch(void* const* d_in, const int* in_sizes, int n_in,
                              void* d_out, int out_size, void* d_ws, size_t ws_size,
                              hipStream_t stream) {
    const float* x   = (const float*)d_in[0];
    const int*   src = (const int*)d_in[1];
    const int*   dst = (const int*)d_in[2];
    const float* W1  = (const float*)d_in[3];
    const float* b1  = (const float*)d_in[4];
    const float* W2  = (const float*)d_in[5];
    const float* b2  = (const float*)d_in[6];
    const float* W3  = (const float*)d_in[7];
    const float* b3  = (const float*)d_in[8];
    float* out = (float*)d_out;

    const int xelems = in_sizes[0];
    const int E = in_sizes[1];
    const int ntiles = (E + 127) >> 7;
    const int grid = ntiles < 512 ? ntiles : 512;

    // ws layout
    const size_t xb_bytes  = (size_t)xelems * 2;
    const size_t off_ssrc  = align256(xb_bytes);
    const size_t off_sdst  = off_ssrc + (size_t)E * 4;
    const size_t off_perm  = off_sdst + (size_t)E * 4;
    const size_t off_cur   = align256(off_perm + (size_t)E * 4);
    const size_t off_hist  = off_cur + NB * 4;
    const size_t need_sort = off_hist + NB * 4;

    if (ws_size >= need_sort) {
        unsigned short* xb = (unsigned short*)d_ws;
        int* ssrc   = (int*)((char*)d_ws + off_ssrc);
        int* sdst   = (int*)((char*)d_ws + off_sdst);
        int* perm   = (int*)((char*)d_ws + off_perm);
        int* cursor = (int*)((char*)d_ws + off_cur);
        int* hist   = (int*)((char*)d_ws + off_hist);

        hipMemsetAsync((char*)d_ws + off_cur, 0, 2 * NB * 4, stream);
        hipLaunchKernelGGL(hist_kernel, dim3(512), dim3(256), 0, stream, src, hist, E);
        hipLaunchKernelGGL(scan_kernel, dim3(1), dim3(NB), 0, stream, hist, cursor);
        hipLaunchKernelGGL(scatter_kernel, dim3(1024), dim3(256), 0, stream,
                           src, dst, cursor, ssrc, sdst, perm, E);
        hipLaunchKernelGGL(cvt_kernel, dim3(2048), dim3(256), 0, stream, x, xb, xelems >> 2);
        hipLaunchKernelGGL((edge_mlp_kernel<2>), dim3(grid), dim3(256), 0, stream,
                           x, xb, ssrc, sdst, perm, W1, b1, W2, b2, W3, b3, out, E, ntiles);
    } else if (ws_size >= xb_bytes) {
        unsigned short* xb = (unsigned short*)d_ws;
        hipLaunchKernelGGL(cvt_kernel, dim3(2048), dim3(256), 0, stream, x, xb, xelems >> 2);
        hipLaunchKernelGGL((edge_mlp_kernel<1>), dim3(grid), dim3(256), 0, stream,
                           x, xb, src, dst, (const int*)nullptr,
                           W1, b1, W2, b2, W3, b3, out, E, ntiles);
    } else {
        hipLaunchKernelGGL((edge_mlp_kernel<0>), dim3(grid), dim3(256), 0, stream,
                           x, (const unsigned short*)nullptr, src, dst, (const int*)nullptr,
                           W1, b1, W2, b2, W3, b3, out, E, ntiles);
    }
}

// Round 7
// 157.766 us; speedup vs baseline: 1.7688x; 1.7688x over previous
//
#include <hip/hip_runtime.h>
#include <hip/hip_bf16.h>

#define HDIM 128
#define NB   1024          // sort bins: bin = src >> 7 (max 99999>>7 = 781 < 1024)
#define NBLK 64            // sort blocks

typedef short bf16x8 __attribute__((ext_vector_type(8)));
typedef float f32x4 __attribute__((ext_vector_type(4)));

__device__ __forceinline__ short f2bf(float f) {
    __hip_bfloat16 h = __float2bfloat16(f);
    return __builtin_bit_cast(short, h);
}

__device__ __forceinline__ float bf2f(short s) {
    unsigned u = ((unsigned)(unsigned short)s) << 16;
    return __builtin_bit_cast(float, u);
}

// B-fragment read from swizzled WT[n][k] LDS image
__device__ __forceinline__ bf16x8 ldB(const short* sW, int n, int chunk) {
    return *(const bf16x8*)(sW + n * HDIM + ((chunk ^ (n & 7)) << 3));
}

__device__ __forceinline__ bf16x8 gatherA_f32(const float* xs, const float* xd, int k0) {
    float4 a0 = *(const float4*)(xs + k0);
    float4 a1 = *(const float4*)(xs + k0 + 4);
    float4 c0 = *(const float4*)(xd + k0);
    float4 c1 = *(const float4*)(xd + k0 + 4);
    bf16x8 r = { f2bf(a0.x * c0.x), f2bf(a0.y * c0.y), f2bf(a0.z * c0.z), f2bf(a0.w * c0.w),
                 f2bf(a1.x * c1.x), f2bf(a1.y * c1.y), f2bf(a1.z * c1.z), f2bf(a1.w * c1.w) };
    return r;
}

__global__ void cvt_kernel(const float* __restrict__ x, unsigned short* __restrict__ xb, int n4) {
    int i = blockIdx.x * blockDim.x + threadIdx.x;
    const int stride = gridDim.x * blockDim.x;
    for (; i < n4; i += stride) {
        float4 v = ((const float4*)x)[i];
        ushort4 o;
        o.x = (unsigned short)f2bf(v.x);
        o.y = (unsigned short)f2bf(v.y);
        o.z = (unsigned short)f2bf(v.z);
        o.w = (unsigned short)f2bf(v.w);
        ((ushort4*)xb)[i] = o;
    }
}

// ---- contention-free counting sort by src>>7 ----
// pass 1: per-block LDS histogram -> bhist[block][bin]  (no global atomics)
__global__ void blockhist_kernel(const int* __restrict__ src, int* __restrict__ bhist,
                                 int E, int per) {
    __shared__ int h[NB];
    for (int i = threadIdx.x; i < NB; i += blockDim.x) h[i] = 0;
    __syncthreads();
    const int s0 = blockIdx.x * per;
    const int s1 = s0 + per < E ? s0 + per : E;
    for (int i = s0 + threadIdx.x; i < s1; i += blockDim.x)
        atomicAdd(&h[src[i] >> 7], 1);
    __syncthreads();
    for (int i = threadIdx.x; i < NB; i += blockDim.x)
        bhist[blockIdx.x * NB + i] = h[i];
}

// pass 2: single block, NB threads; thread t owns bin t.
// gbase[b][t] = (exclusive scan over bins of totals) + (prefix over blocks < b)
__global__ void scanbase_kernel(const int* __restrict__ bhist, int* __restrict__ gbase) {
    __shared__ int s[NB];
    const int t = threadIdx.x;
    int tot = 0;
    for (int b = 0; b < NBLK; ++b) tot += bhist[b * NB + t];
    s[t] = tot;
    __syncthreads();
    for (int off = 1; off < NB; off <<= 1) {
        int add = (t >= off) ? s[t - off] : 0;
        __syncthreads();
        s[t] += add;
        __syncthreads();
    }
    int base = s[t] - tot;   // exclusive over bins
    for (int b = 0; b < NBLK; ++b) {
        gbase[b * NB + t] = base;
        base += bhist[b * NB + t];
    }
}

// pass 3: place edges; ranks via LDS atomics only (per-CU, fast)
__global__ void scatter2_kernel(const int* __restrict__ src, const int* __restrict__ dst,
                                const int* __restrict__ gbase,
                                int* __restrict__ ssrc, int* __restrict__ sdst,
                                int* __restrict__ perm, int E, int per) {
    __shared__ int cur[NB];
    for (int i = threadIdx.x; i < NB; i += blockDim.x)
        cur[i] = gbase[blockIdx.x * NB + i];
    __syncthreads();
    const int s0 = blockIdx.x * per;
    const int s1 = s0 + per < E ? s0 + per : E;
    for (int i = s0 + threadIdx.x; i < s1; i += blockDim.x) {
        int sv = src[i];
        int p = atomicAdd(&cur[sv >> 7], 1);
        ssrc[p] = sv;
        sdst[p] = dst[i];
        perm[p] = i;
    }
}

// MODE: 0 = fp32 direct (no ws), 1 = bf16 unsorted (R2 path), 2 = bf16 sorted + perm scatter
// 256 threads, 4 waves x 32 edges; LDS 80 KB -> 2 blocks/CU (8 waves/CU).
template<int MODE>
__global__ __launch_bounds__(256, 2)
void edge_mlp_kernel(const float* __restrict__ x,
                     const unsigned short* __restrict__ xb,
                     const int* __restrict__ ssrc,
                     const int* __restrict__ sdst,
                     const int* __restrict__ perm,
                     const float* __restrict__ W1, const float* __restrict__ b1,
                     const float* __restrict__ W2, const float* __restrict__ b2,
                     const float* __restrict__ W3, const float* __restrict__ b3,
                     float* __restrict__ out, int E, int ntiles)
{
    __shared__ short sW1[HDIM * HDIM];      // 32 KB
    __shared__ short sW2[HDIM * HDIM];      // 32 KB
    __shared__ short sH1[4][32 * 64];       // 16 KB

    const int tid = threadIdx.x;

    // stage weights fp32 [k][n] -> LDS bf16 WT[n][k], swizzled
    {
        const int n  = tid & 127;
        const int kh = tid >> 7;
        for (int c = 0; c < 8; ++c) {
            const int kc = kh * 8 + c;
            const int k0 = kc * 8;
            short v1[8], v2[8];
            #pragma unroll
            for (int j = 0; j < 8; ++j) {
                v1[j] = f2bf(W1[(k0 + j) * HDIM + n]);
                v2[j] = f2bf(W2[(k0 + j) * HDIM + n]);
            }
            const int off = n * HDIM + ((kc ^ (n & 7)) << 3);
            bf16x8 t1 = { v1[0], v1[1], v1[2], v1[3], v1[4], v1[5], v1[6], v1[7] };
            bf16x8 t2 = { v2[0], v2[1], v2[2], v2[3], v2[4], v2[5], v2[6], v2[7] };
            *(bf16x8*)(sW1 + off) = t1;
            *(bf16x8*)(sW2 + off) = t2;
        }
    }
    __syncthreads();

    const int w    = tid >> 6;
    const int lane = tid & 63;
    const int g    = lane >> 4;
    const int e16  = lane & 15;
    short* myH1 = &sH1[w][0];

    float b1v[8], b2v[8], w3v[8];
    #pragma unroll
    for (int nt = 0; nt < 8; ++nt) {
        b1v[nt] = b1[nt * 16 + e16];
        b2v[nt] = b2[nt * 16 + e16];
        w3v[nt] = W3[nt * 16 + e16];
    }
    const float b3s = b3[0];

    // tile range
    int t0, t1e, tstep;
    if constexpr (MODE == 2) {
        // XCD-contiguous mapping: assume XCD = blockIdx % 8 (round-robin dispatch).
        // Blocks of XCD k process one contiguous chunk range -> src window ~3.2 MB,
        // fits that XCD's 4 MB L2.
        int c;
        if (gridDim.x == 512) c = (blockIdx.x & 7) * 64 + (blockIdx.x >> 3);
        else                  c = blockIdx.x;
        const int tp = (ntiles + gridDim.x - 1) / gridDim.x;
        t0 = c * tp;
        t1e = t0 + tp < ntiles ? t0 + tp : ntiles;
        tstep = 1;
    } else {
        t0 = blockIdx.x;
        t1e = ntiles;
        tstep = gridDim.x;
    }
    if (t0 >= t1e) return;

    int tile = t0;
    int s0, d0, s1, d1;
    {
        const int base = (tile << 7) + (w << 5);
        int a0 = base + e16;       a0 = a0 < E ? a0 : 0;
        int a1 = base + 16 + e16;  a1 = a1 < E ? a1 : 0;
        s0 = ssrc[a0]; d0 = sdst[a0]; s1 = ssrc[a1]; d1 = sdst[a1];
    }
    bf16x8 rS0[4], rD0[4], rS1[4], rD1[4];
    if constexpr (MODE >= 1) {
        const unsigned short* pxs0 = xb + (size_t)s0 * HDIM;
        const unsigned short* pxd0 = xb + (size_t)d0 * HDIM;
        const unsigned short* pxs1 = xb + (size_t)s1 * HDIM;
        const unsigned short* pxd1 = xb + (size_t)d1 * HDIM;
        #pragma unroll
        for (int t = 0; t < 4; ++t) {
            const int k0 = t * 32 + g * 8;
            rS0[t] = *(const bf16x8*)(pxs0 + k0);
            rD0[t] = *(const bf16x8*)(pxd0 + k0);
            rS1[t] = *(const bf16x8*)(pxs1 + k0);
            rD1[t] = *(const bf16x8*)(pxd1 + k0);
        }
    }

    for (;;) {
        const int nxt = tile + tstep;
        const bool hasNext = nxt < t1e;

        int ns0, nd0, ns1, nd1;
        {
            const int nb = hasNext ? (nxt << 7) + (w << 5) : 0;
            int a0 = nb + e16;       a0 = a0 < E ? a0 : 0;
            int a1 = nb + 16 + e16;  a1 = a1 < E ? a1 : 0;
            ns0 = ssrc[a0]; nd0 = sdst[a0]; ns1 = ssrc[a1]; nd1 = sdst[a1];
        }

        const int base = (tile << 7) + (w << 5);

        // ---------- GEMM1 ----------
        f32x4 acc[2][8];
        #pragma unroll
        for (int nt = 0; nt < 8; ++nt) {
            f32x4 iv = { b1v[nt], b1v[nt], b1v[nt], b1v[nt] };
            acc[0][nt] = iv;
            acc[1][nt] = iv;
        }

        if constexpr (MODE >= 1) {
            #pragma unroll
            for (int t = 0; t < 4; ++t) {
                bf16x8 a0, a1;
                #pragma unroll
                for (int j = 0; j < 8; ++j) {
                    a0[j] = f2bf(bf2f(rS0[t][j]) * bf2f(rD0[t][j]));
                    a1[j] = f2bf(bf2f(rS1[t][j]) * bf2f(rD1[t][j]));
                }
                #pragma unroll
                for (int nt = 0; nt < 8; ++nt) {
                    bf16x8 bb = ldB(sW1, nt * 16 + e16, t * 4 + g);
                    acc[0][nt] = __builtin_amdgcn_mfma_f32_16x16x32_bf16(a0, bb, acc[0][nt], 0, 0, 0);
                    acc[1][nt] = __builtin_amdgcn_mfma_f32_16x16x32_bf16(a1, bb, acc[1][nt], 0, 0, 0);
                }
            }
        } else {
            const float* xs0 = x + (size_t)s0 * HDIM;
            const float* xd0 = x + (size_t)d0 * HDIM;
            const float* xs1 = x + (size_t)s1 * HDIM;
            const float* xd1 = x + (size_t)d1 * HDIM;
            #pragma unroll
            for (int t = 0; t < 4; ++t) {
                const int k0 = t * 32 + g * 8;
                bf16x8 a0 = gatherA_f32(xs0, xd0, k0);
                bf16x8 a1 = gatherA_f32(xs1, xd1, k0);
                #pragma unroll
                for (int nt = 0; nt < 8; ++nt) {
                    bf16x8 bb = ldB(sW1, nt * 16 + e16, t * 4 + g);
                    acc[0][nt] = __builtin_amdgcn_mfma_f32_16x16x32_bf16(a0, bb, acc[0][nt], 0, 0, 0);
                    acc[1][nt] = __builtin_amdgcn_mfma_f32_16x16x32_bf16(a1, bb, acc[1][nt], 0, 0, 0);
                }
            }
        }

        // issue next tile's raw gathers; latency hides under GEMM2
        bf16x8 nS0[4], nD0[4], nS1[4], nD1[4];
        if constexpr (MODE >= 1) {
            const unsigned short* pxs0 = xb + (size_t)ns0 * HDIM;
            const unsigned short* pxd0 = xb + (size_t)nd0 * HDIM;
            const unsigned short* pxs1 = xb + (size_t)ns1 * HDIM;
            const unsigned short* pxd1 = xb + (size_t)nd1 * HDIM;
            #pragma unroll
            for (int t = 0; t < 4; ++t) {
                const int k0 = t * 32 + g * 8;
                nS0[t] = *(const bf16x8*)(pxs0 + k0);
                nD0[t] = *(const bf16x8*)(pxd0 + k0);
                nS1[t] = *(const bf16x8*)(pxs1 + k0);
                nD1[t] = *(const bf16x8*)(pxd1 + k0);
            }
        }

        // ---------- GEMM2 ----------
        f32x4 acc2[2][8];
        #pragma unroll
        for (int nt = 0; nt < 8; ++nt) {
            f32x4 iv = { b2v[nt], b2v[nt], b2v[nt], b2v[nt] };
            acc2[0][nt] = iv;
            acc2[1][nt] = iv;
        }
        #pragma unroll
        for (int khf = 0; khf < 2; ++khf) {
            #pragma unroll
            for (int ntl = 0; ntl < 4; ++ntl) {
                const int nt = khf * 4 + ntl;
                #pragma unroll
                for (int mt = 0; mt < 2; ++mt) {
                    #pragma unroll
                    for (int r = 0; r < 4; ++r) {
                        const int e  = mt * 16 + g * 4 + r;
                        const int kk = ntl * 16 + e16;
                        float v = acc[mt][nt][r];
                        v = v > 0.0f ? v : 0.0f;
                        myH1[e * 64 + (((kk >> 3) ^ (e & 7)) << 3) + (kk & 7)] = f2bf(v);
                    }
                }
            }
            #pragma unroll
            for (int tl = 0; tl < 2; ++tl) {
                const int ck = tl * 4 + g;
                bf16x8 a0 = *(const bf16x8*)(myH1 + e16 * 64 + ((ck ^ (e16 & 7)) << 3));
                bf16x8 a1 = *(const bf16x8*)(myH1 + (e16 + 16) * 64 + ((ck ^ ((e16 + 16) & 7)) << 3));
                const int t2 = khf * 2 + tl;
                #pragma unroll
                for (int nt = 0; nt < 8; ++nt) {
                    bf16x8 bb = ldB(sW2, nt * 16 + e16, t2 * 4 + g);
                    acc2[0][nt] = __builtin_amdgcn_mfma_f32_16x16x32_bf16(a0, bb, acc2[0][nt], 0, 0, 0);
                    acc2[1][nt] = __builtin_amdgcn_mfma_f32_16x16x32_bf16(a1, bb, acc2[1][nt], 0, 0, 0);
                }
            }
        }

        // ---------- epilogue ----------
        #pragma unroll
        for (int mt = 0; mt < 2; ++mt) {
            float p0 = 0.f, p1 = 0.f, p2 = 0.f, p3 = 0.f;
            #pragma unroll
            for (int nt = 0; nt < 8; ++nt) {
                f32x4 v = acc2[mt][nt];
                float r0 = v[0] > 0.f ? v[0] : 0.f;
                float r1 = v[1] > 0.f ? v[1] : 0.f;
                float r2 = v[2] > 0.f ? v[2] : 0.f;
                float r3 = v[3] > 0.f ? v[3] : 0.f;
                p0 += r0 * w3v[nt];
                p1 += r1 * w3v[nt];
                p2 += r2 * w3v[nt];
                p3 += r3 * w3v[nt];
            }
            #pragma unroll
            for (int off = 1; off < 16; off <<= 1) {
                p0 += __shfl_xor(p0, off);
                p1 += __shfl_xor(p1, off);
                p2 += __shfl_xor(p2, off);
                p3 += __shfl_xor(p3, off);
            }
            if (e16 == 0) {
                const int eb = base + mt * 16 + g * 4;
                float pv[4] = { p0, p1, p2, p3 };
                #pragma unroll
                for (int j = 0; j < 4; ++j) {
                    if (eb + j < E) {
                        if constexpr (MODE == 2) out[perm[eb + j]] = pv[j] + b3s;
                        else                     out[eb + j]       = pv[j] + b3s;
                    }
                }
            }
        }

        if (!hasNext) break;
        tile = nxt;
        s0 = ns0; d0 = nd0; s1 = ns1; d1 = nd1;
        if constexpr (MODE >= 1) {
            #pragma unroll
            for (int t = 0; t < 4; ++t) {
                rS0[t] = nS0[t]; rD0[t] = nD0[t];
                rS1[t] = nS1[t]; rD1[t] = nD1[t];
            }
        }
    }
}

static inline size_t align256(size_t v) { return (v + 255) & ~(size_t)255; }

extern "C" void kernel_launch(void* const* d_in, const int* in_sizes, int n_in,
                              void* d_out, int out_size, void* d_ws, size_t ws_size,
                              hipStream_t stream) {
    const float* x   = (const float*)d_in[0];
    const int*   src = (const int*)d_in[1];
    const int*   dst = (const int*)d_in[2];
    const float* W1  = (const float*)d_in[3];
    const float* b1  = (const float*)d_in[4];
    const float* W2  = (const float*)d_in[5];
    const float* b2  = (const float*)d_in[6];
    const float* W3  = (const float*)d_in[7];
    const float* b3  = (const float*)d_in[8];
    float* out = (float*)d_out;

    const int xelems = in_sizes[0];
    const int E = in_sizes[1];
    const int ntiles = (E + 127) >> 7;
    const int grid = ntiles < 512 ? ntiles : 512;

    // ws layout
    const size_t xb_bytes  = (size_t)xelems * 2;
    const size_t off_ssrc  = align256(xb_bytes);
    const size_t off_sdst  = off_ssrc + (size_t)E * 4;
    const size_t off_perm  = off_sdst + (size_t)E * 4;
    const size_t off_bhist = align256(off_perm + (size_t)E * 4);
    const size_t off_gbase = off_bhist + (size_t)NBLK * NB * 4;
    const size_t need_sort = off_gbase + (size_t)NBLK * NB * 4;

    if (ws_size >= need_sort) {
        unsigned short* xb = (unsigned short*)d_ws;
        int* ssrc  = (int*)((char*)d_ws + off_ssrc);
        int* sdst  = (int*)((char*)d_ws + off_sdst);
        int* perm  = (int*)((char*)d_ws + off_perm);
        int* bhist = (int*)((char*)d_ws + off_bhist);
        int* gbase = (int*)((char*)d_ws + off_gbase);

        const int per = (E + NBLK - 1) / NBLK;
        hipLaunchKernelGGL(blockhist_kernel, dim3(NBLK), dim3(256), 0, stream, src, bhist, E, per);
        hipLaunchKernelGGL(scanbase_kernel, dim3(1), dim3(NB), 0, stream, bhist, gbase);
        hipLaunchKernelGGL(scatter2_kernel, dim3(NBLK), dim3(256), 0, stream,
                           src, dst, gbase, ssrc, sdst, perm, E, per);
        hipLaunchKernelGGL(cvt_kernel, dim3(2048), dim3(256), 0, stream, x, xb, xelems >> 2);
        hipLaunchKernelGGL((edge_mlp_kernel<2>), dim3(grid), dim3(256), 0, stream,
                           x, xb, ssrc, sdst, perm, W1, b1, W2, b2, W3, b3, out, E, ntiles);
    } else if (ws_size >= xb_bytes) {
        unsigned short* xb = (unsigned short*)d_ws;
        hipLaunchKernelGGL(cvt_kernel, dim3(2048), dim3(256), 0, stream, x, xb, xelems >> 2);
        hipLaunchKernelGGL((edge_mlp_kernel<1>), dim3(grid), dim3(256), 0, stream,
                           x, xb, src, dst, (const int*)nullptr,
                           W1, b1, W2, b2, W3, b3, out, E, ntiles);
    } else {
        hipLaunchKernelGGL((edge_mlp_kernel<0>), dim3(grid), dim3(256), 0, stream,
                           x, (const unsigned short*)nullptr, src, dst, (const int*)nullptr,
                           W1, b1, W2, b2, W3, b3, out, E, ntiles);
    }
}